// Round 8
// baseline (47.338 us; speedup 1.0000x reference)
//
#include <hip/hip_runtime.h>

// out[b,n,:] = tables[template_id[b], atom_role[b,n], :]   (all fp32)
// B=4096, N=128, T=64, R=16, D=128.
// Write-BW-bound. Best: R5 (flat gather, unroll8, plain stores) 46.4us.
//
// R8 isolates the read-path-interference hypothesis: same geometry as R5,
// plain stores, but the block's single 8KB table slice is staged into LDS
// once (coalesced dwordx4), so the steady-state loop is ds_read_b128 ->
// global_store_dwordx4 with ZERO global loads — the store stream becomes
// structurally identical to the 7.0 TB/s fill kernel. (R4 tested LDS but
// confounded with nt-stores, which R5 showed cost 7us alone.)

constexpr int B = 4096;
constexpr int N = 128;
constexpr int R = 16;
constexpr int D = 128;
constexpr int BLOCK  = 256;
constexpr int UNROLL = 8;
constexpr int F4_PER_BLOCK = BLOCK * UNROLL;            // 2048 f4 = 64 rows
constexpr int GRID = (B * N * (D / 4)) / F4_PER_BLOCK;  // 8192

typedef float floatx4 __attribute__((ext_vector_type(4)));

__global__ __launch_bounds__(BLOCK) void role_embed_gather(
    const int* __restrict__ template_id,   // [B]
    const int* __restrict__ atom_role,     // [B*N]
    const float* __restrict__ tables,      // [T*R*D]
    floatx4* __restrict__ out)             // [B*N*D/4]
{
    __shared__ floatx4 s_tab[R * D / 4];   // 8 KB = 512 float4

    const int tid = threadIdx.x;
    const int blk = blockIdx.x;

    // Block covers rows [blk*64, blk*64+64) -> batch b = blk>>1 (uniform).
    const int t = template_id[blk >> 1];   // scalar s_load
    const floatx4* src =
        reinterpret_cast<const floatx4*>(tables + t * (R * D));

    // Stage the 8KB slice: 2 coalesced dwordx4 per thread.
    s_tab[tid]         = src[tid];
    s_tab[tid + BLOCK] = src[tid + BLOCK];

    const int col  = tid & 31;                  // f4 column in D=128 row
    const int row0 = blk * 64 + (tid >> 5);     // this thread's base row

    // 8 role loads (32-lane broadcast, L1-hit), independent of staging.
    int rl[UNROLL];
#pragma unroll
    for (int k = 0; k < UNROLL; ++k)
        rl[k] = atom_role[row0 + k * 8];

    __syncthreads();

    // Steady state: ds_read_b128 -> plain global_store_dwordx4.
    // Lane group reads 512B consecutive from one LDS row: 2-way bank
    // aliasing only (free). Stores: contiguous 16KB per iteration.
    floatx4* ob = out + (size_t)blk * F4_PER_BLOCK;
#pragma unroll
    for (int k = 0; k < UNROLL; ++k) {
        const floatx4 v = s_tab[rl[k] * (D / 4) + col];
        ob[k * BLOCK + tid] = v;
    }
}

extern "C" void kernel_launch(void* const* d_in, const int* in_sizes, int n_in,
                              void* d_out, int out_size, void* d_ws, size_t ws_size,
                              hipStream_t stream) {
    const int*   template_id = (const int*)d_in[0];
    const int*   atom_role   = (const int*)d_in[1];
    const float* tables      = (const float*)d_in[2];
    floatx4*     out         = (floatx4*)d_out;

    role_embed_gather<<<GRID, BLOCK, 0, stream>>>(template_id, atom_role, tables, out);
}